// Round 1
// baseline (123.640 us; speedup 1.0000x reference)
//
#include <hip/hip_runtime.h>
#include <hip/hip_bf16.h>

// ---------------------------------------------------------------------------
// Triplet loss:
//   D1[i,j] = || (v_f[j]+eps) - i_f[i] ||,  D2[i,j] = || (i_f[j]+eps) - v_f[i] ||
//   per row: same_max = max over same-label D, diff_min = min over diff-label D
//   loss = sum relu(same_max - diff_min + 1.2) over both matrices.
// sq-domain trick: reduce on squared distances, sqrt once per row.
// ---------------------------------------------------------------------------

#define MDIM 4096
#define KDIM 1024
#define BM 128
#define BN 128
#define BK 32

typedef __attribute__((ext_vector_type(4))) float  f32x4;
typedef __attribute__((ext_vector_type(8))) short  bf16x8;

__device__ __forceinline__ void gload16(const void* g, void* l) {
  __builtin_amdgcn_global_load_lds(
      (const __attribute__((address_space(1))) void*)g,
      (__attribute__((address_space(3))) void*)l,
      16, 0, 0);
}

__device__ __forceinline__ unsigned short f2bf(float x) {
  unsigned int u = __float_as_uint(x);
  unsigned int r = (u + 0x7FFFu + ((u >> 16) & 1u)) >> 16;  // RNE
  return (unsigned short)r;
}

// --- prep: f32 -> bf16 copies, row norms of x and x+eps (exact f32) --------
__global__ __launch_bounds__(256) void prep_kernel(
    const float* __restrict__ vf, const float* __restrict__ iff,
    unsigned short* __restrict__ vb, unsigned short* __restrict__ ib,
    float* __restrict__ nv, float* __restrict__ ni,
    float* __restrict__ nvp, float* __restrict__ nip) {
  const int b = blockIdx.x;             // 0..8191
  const int mat = b >> 12;              // 0 = v_f, 1 = i_f
  const int row = b & 4095;
  const float* X = mat ? iff : vf;
  unsigned short* Xb = mat ? ib : vb;
  float* n0 = mat ? ni : nv;
  float* n1 = mat ? nip : nvp;

  const int t = threadIdx.x;
  const float4* xr4 = (const float4*)(X + (size_t)row * KDIM);
  ushort4* xb4 = (ushort4*)(Xb + (size_t)row * KDIM);

  float4 v = xr4[t];
  float s0 = v.x * v.x + v.y * v.y + v.z * v.z + v.w * v.w;
  float ex = v.x + 1e-6f, ey = v.y + 1e-6f, ez = v.z + 1e-6f, ew = v.w + 1e-6f;
  float s1 = ex * ex + ey * ey + ez * ez + ew * ew;
  ushort4 o;
  o.x = f2bf(v.x); o.y = f2bf(v.y); o.z = f2bf(v.z); o.w = f2bf(v.w);
  xb4[t] = o;

  for (int off = 32; off; off >>= 1) {
    s0 += __shfl_down(s0, off);
    s1 += __shfl_down(s1, off);
  }
  __shared__ float r0[4], r1[4];
  const int w = t >> 6, lane = t & 63;
  if (lane == 0) { r0[w] = s0; r1[w] = s1; }
  __syncthreads();
  if (t == 0) {
    n0[row] = r0[0] + r0[1] + r0[2] + r0[3];
    n1[row] = r1[0] + r1[1] + r1[2] + r1[3];
  }
}

// --- init the atomic max/min buffers ---------------------------------------
__global__ __launch_bounds__(256) void init_kernel(int* __restrict__ same_sq,
                                                   int* __restrict__ diff_sq) {
  const int i = blockIdx.x * 256 + threadIdx.x;  // 8192 total
  same_sq[i] = 0;                                // sq >= 0, so 0 is max-identity
  diff_sq[i] = 0x7F800000;                       // +inf
}

// --- fused GEMM + distance + masked row max/min ----------------------------
// dir 0: A = i_f (anchor), B = v_f (+eps norms).  dir 1: A = v_f, B = i_f.
__global__ __launch_bounds__(256, 2) void tri_gemm(
    const unsigned short* __restrict__ vb, const unsigned short* __restrict__ ib,
    const float* __restrict__ nv, const float* __restrict__ ni,
    const float* __restrict__ nvp, const float* __restrict__ nip,
    const int* __restrict__ y,
    int* __restrict__ same_sq, int* __restrict__ diff_sq) {
  __shared__ unsigned short At[BM * BK];
  __shared__ unsigned short Bt[BN * BK];
  __shared__ int   yrow[BM], ycol[BN];
  __shared__ float nAr[BM], nBc[BN];

  const int dir = blockIdx.z;
  const unsigned short* Amat = dir ? vb : ib;
  const unsigned short* Bmat = dir ? ib : vb;
  const float* nA = dir ? nv : ni;
  const float* nB = dir ? nip : nvp;

  const int row0 = blockIdx.y * BM;
  const int col0 = blockIdx.x * BN;

  const int t = threadIdx.x;
  const int w = t >> 6, lane = t & 63;
  const int lr = lane & 15, lg = lane >> 4;
  const int wr = w >> 1, wc = w & 1;

  if (t < BM) {
    yrow[t] = y[row0 + t];
    nAr[t] = nA[row0 + t];
  } else {
    const int c = t - BM;
    ycol[c] = y[col0 + c];
    nBc[c] = nB[col0 + c];
  }

  f32x4 acc[4][4] = {};

  for (int k0 = 0; k0 < KDIM; k0 += BK) {
    __syncthreads();  // prior iteration's LDS reads done before overwrite
#pragma unroll
    for (int c = 0; c < 2; ++c) {
      const int e = c * 2048 + w * 512 + lane * 8;   // element in 128x32 tile
      const int r = e >> 5, col = e & 31;
      gload16(Amat + (size_t)(row0 + r) * KDIM + k0 + col, &At[c * 2048 + w * 512]);
      gload16(Bmat + (size_t)(col0 + r) * KDIM + k0 + col, &Bt[c * 2048 + w * 512]);
    }
    asm volatile("s_waitcnt vmcnt(0)" ::: "memory");
    __syncthreads();

    bf16x8 af[4], bfr[4];
#pragma unroll
    for (int m = 0; m < 4; ++m)
      af[m] = *(const bf16x8*)&At[(wr * 64 + m * 16 + lr) * BK + lg * 8];
#pragma unroll
    for (int n = 0; n < 4; ++n)
      bfr[n] = *(const bf16x8*)&Bt[(wc * 64 + n * 16 + lr) * BK + lg * 8];
#pragma unroll
    for (int m = 0; m < 4; ++m)
#pragma unroll
      for (int n = 0; n < 4; ++n)
        acc[m][n] = __builtin_amdgcn_mfma_f32_16x16x32_bf16(af[m], bfr[n], acc[m][n], 0, 0, 0);
  }

  // epilogue: sq distance + mask + per-row reduce over this tile's 128 cols
  const int rbase = dir * MDIM + row0;
#pragma unroll
  for (int m = 0; m < 4; ++m) {
#pragma unroll
    for (int r = 0; r < 4; ++r) {
      const int row_loc = wr * 64 + m * 16 + lg * 4 + r;
      const float na = nAr[row_loc];
      const int yl = yrow[row_loc];
      float smax = 0.0f;
      float dmin = __int_as_float(0x7F800000);
#pragma unroll
      for (int n = 0; n < 4; ++n) {
        const int col_loc = wc * 64 + n * 16 + lr;
        const float sq = fmaxf(na + nBc[col_loc] - 2.0f * acc[m][n][r], 0.0f);
        if (ycol[col_loc] == yl) smax = fmaxf(smax, sq);
        else                     dmin = fminf(dmin, sq);
      }
#pragma unroll
      for (int off = 1; off < 16; off <<= 1) {
        smax = fmaxf(smax, __shfl_xor(smax, off));
        dmin = fminf(dmin, __shfl_xor(dmin, off));
      }
      if (lr == 0) {
        // nonneg floats: int compare == float compare -> order-independent
        atomicMax(&same_sq[rbase + row_loc], __float_as_int(smax));
        atomicMin(&diff_sq[rbase + row_loc], __float_as_int(dmin));
      }
    }
  }
}

// --- finalize: sqrt, relu, sum ---------------------------------------------
__global__ __launch_bounds__(256) void finalize_kernel(
    const int* __restrict__ same_sq, const int* __restrict__ diff_sq,
    float* __restrict__ out) {
  const int i = blockIdx.x * 256 + threadIdx.x;  // 8192 total
  const float sm = sqrtf(__int_as_float(same_sq[i]));
  const float dm = sqrtf(__int_as_float(diff_sq[i]));  // +inf if no diff label
  float l = fmaxf(sm - dm + 1.2f, 0.0f);
  for (int off = 32; off; off >>= 1) l += __shfl_down(l, off);
  __shared__ float part[4];
  const int w = threadIdx.x >> 6, lane = threadIdx.x & 63;
  if (lane == 0) part[w] = l;
  __syncthreads();
  if (threadIdx.x == 0) atomicAdd(out, part[0] + part[1] + part[2] + part[3]);
}

extern "C" void kernel_launch(void* const* d_in, const int* in_sizes, int n_in,
                              void* d_out, int out_size, void* d_ws, size_t ws_size,
                              hipStream_t stream) {
  const float* vf = (const float*)d_in[0];
  const float* iff = (const float*)d_in[1];
  const int* y = (const int*)d_in[2];
  float* out = (float*)d_out;

  char* ws = (char*)d_ws;
  unsigned short* vb = (unsigned short*)ws;                       // 8 MB
  unsigned short* ib = (unsigned short*)(ws + (8u << 20));        // 8 MB
  float* nv  = (float*)(ws + (16u << 20));
  float* ni  = nv + 4096;
  float* nvp = nv + 2 * 4096;
  float* nip = nv + 3 * 4096;
  int* same_sq = (int*)(nv + 4 * 4096);                           // [2][4096]
  int* diff_sq = same_sq + 2 * 4096;                              // [2][4096]

  hipMemsetAsync(d_out, 0, sizeof(float), stream);
  init_kernel<<<32, 256, 0, stream>>>(same_sq, diff_sq);
  prep_kernel<<<8192, 256, 0, stream>>>(vf, iff, vb, ib, nv, ni, nvp, nip);
  tri_gemm<<<dim3(32, 32, 2), 256, 0, stream>>>(vb, ib, nv, ni, nvp, nip, y,
                                                same_sq, diff_sq);
  finalize_kernel<<<32, 256, 0, stream>>>(same_sq, diff_sq, out);
}

// Round 2
// 102.255 us; speedup vs baseline: 1.2091x; 1.2091x over previous
//
#include <hip/hip_runtime.h>
#include <hip/hip_bf16.h>

// ---------------------------------------------------------------------------
// Triplet loss, 8-phase 256^2 MFMA GEMM port (m201 template):
//   D1[i,j] = || (v_f[j]+eps) - i_f[i] ||,  D2[i,j] = || (i_f[j]+eps) - v_f[i] ||
//   per row: same_max = max over same-label D, diff_min = min over diff-label D
//   loss = sum relu(same_max - diff_min + 1.2) over both matrices.
// sq-domain trick: reduce on squared distances, sqrt once per row.
// ---------------------------------------------------------------------------

#define MDIM 4096
#define KDIM 1024
#define NT   16      // K-tiles of 64

typedef __attribute__((ext_vector_type(4))) float  f32x4;
typedef __attribute__((ext_vector_type(8))) short  bf16x8;

__device__ __forceinline__ void gload16(const void* g, void* l) {
  __builtin_amdgcn_global_load_lds(
      (const __attribute__((address_space(1))) void*)g,
      (__attribute__((address_space(3))) void*)l,
      16, 0, 0);
}

__device__ __forceinline__ unsigned short f2bf(float x) {
  unsigned int u = __float_as_uint(x);
  unsigned int r = (u + 0x7FFFu + ((u >> 16) & 1u)) >> 16;  // RNE
  return (unsigned short)r;
}

#define BAR() do { asm volatile("" ::: "memory"); \
                   __builtin_amdgcn_s_barrier();  \
                   asm volatile("" ::: "memory"); } while (0)

// --- prep: f32 -> bf16 copies, row norms of x and x+eps (exact f32) --------
__global__ __launch_bounds__(256) void prep_kernel(
    const float* __restrict__ vf, const float* __restrict__ iff,
    unsigned short* __restrict__ vb, unsigned short* __restrict__ ib,
    float* __restrict__ nv, float* __restrict__ ni,
    float* __restrict__ nvp, float* __restrict__ nip) {
  const int b = blockIdx.x;             // 0..8191
  const int mat = b >> 12;              // 0 = v_f, 1 = i_f
  const int row = b & 4095;
  const float* X = mat ? iff : vf;
  unsigned short* Xb = mat ? ib : vb;
  float* n0 = mat ? ni : nv;
  float* n1 = mat ? nip : nvp;

  const int t = threadIdx.x;
  const float4* xr4 = (const float4*)(X + (size_t)row * KDIM);
  ushort4* xb4 = (ushort4*)(Xb + (size_t)row * KDIM);

  float4 v = xr4[t];
  float s0 = v.x * v.x + v.y * v.y + v.z * v.z + v.w * v.w;
  float ex = v.x + 1e-6f, ey = v.y + 1e-6f, ez = v.z + 1e-6f, ew = v.w + 1e-6f;
  float s1 = ex * ex + ey * ey + ez * ez + ew * ew;
  ushort4 o;
  o.x = f2bf(v.x); o.y = f2bf(v.y); o.z = f2bf(v.z); o.w = f2bf(v.w);
  xb4[t] = o;

  for (int off = 32; off; off >>= 1) {
    s0 += __shfl_down(s0, off);
    s1 += __shfl_down(s1, off);
  }
  __shared__ float r0[4], r1[4];
  const int w = t >> 6, lane = t & 63;
  if (lane == 0) { r0[w] = s0; r1[w] = s1; }
  __syncthreads();
  if (t == 0) {
    n0[row] = r0[0] + r0[1] + r0[2] + r0[3];
    n1[row] = r1[0] + r1[1] + r1[2] + r1[3];
  }
}

// --- init the atomic max/min buffers ---------------------------------------
__global__ __launch_bounds__(256) void init_kernel(int* __restrict__ same_sq,
                                                   int* __restrict__ diff_sq) {
  const int i = blockIdx.x * 256 + threadIdx.x;  // 8192 total
  same_sq[i] = 0;                                // sq >= 0, so 0 is max-identity
  diff_sq[i] = 0x7F800000;                       // +inf
}

// --- fused 256x256 8-phase GEMM + distance + masked row max/min ------------
// dir 0: A = i_f (anchor), B = v_f (+eps norms).  dir 1: A = v_f, B = i_f.
__global__ __launch_bounds__(512, 2) void tri_gemm(
    const unsigned short* __restrict__ vb, const unsigned short* __restrict__ ib,
    const float* __restrict__ nv, const float* __restrict__ ni,
    const float* __restrict__ nvp, const float* __restrict__ nip,
    const int* __restrict__ y,
    int* __restrict__ same_sq, int* __restrict__ diff_sq) {
  // K-tile buffer: [256 rows][64 k] bf16, row = 128 B, 8 chunks of 16 B.
  // XOR swizzle: data for (row, chunk) lives at (row, chunk ^ (row&7)).
  // global_load_lds dest stays linear; source address is pre-swizzled.
  __shared__ unsigned short Abuf[2][256][64];   // 64 KiB
  __shared__ unsigned short Bbuf[2][256][64];   // 64 KiB
  __shared__ int   yrow[256], ycol[256];
  __shared__ float nAr[256], nBc[256];

  const int dir = blockIdx.z;
  const unsigned short* Amat = dir ? vb : ib;
  const unsigned short* Bmat = dir ? ib : vb;
  const float* nA = dir ? nv : ni;
  const float* nB = dir ? nip : nvp;

  const int row0 = blockIdx.y * 256;
  const int col0 = blockIdx.x * 256;

  const int t = threadIdx.x;
  const int w = t >> 6, lane = t & 63;
  const int lr = lane & 15, lg = lane >> 4;
  const int wr = w >> 2, wc = w & 3;            // 2 x 4 waves -> 128 x 64 tile

  // stage one half-tile (128 rows x 64 k = 16 KB) = 2 gload16 per thread
  auto stage = [&](const unsigned short* __restrict__ X, int tile0,
                   unsigned short (&buf)[256][64], int h, int k0s) {
#pragma unroll
    for (int r = 0; r < 2; ++r) {
      const int row = h * 128 + r * 64 + (t >> 3);
      const int chunk = t & 7;
      const unsigned short* src =
          X + (size_t)(tile0 + row) * KDIM + k0s + ((chunk ^ (row & 7)) << 3);
      gload16(src, &buf[h * 128 + r * 64 + (w << 3)][0]);
    }
  };
  auto ldA = [&](int c, int mh, int m, int ks) -> bf16x8 {
    const int row = wr * 128 + mh * 64 + m * 16 + lr;
    const int chunk = ((ks << 2) | lg) ^ (row & 7);
    return *(const bf16x8*)&Abuf[c][row][chunk << 3];
  };
  auto ldB = [&](int c, int nh, int n, int ks) -> bf16x8 {
    const int col = wc * 64 + nh * 32 + n * 16 + lr;
    const int chunk = ((ks << 2) | lg) ^ (col & 7);
    return *(const bf16x8*)&Bbuf[c][col][chunk << 3];
  };

  // ---- prologue: tile 0 fully + tile 1 A-half0; labels/norms ----
  stage(Amat, row0, Abuf[0], 0, 0);
  stage(Amat, row0, Abuf[0], 1, 0);
  stage(Bmat, col0, Bbuf[0], 0, 0);
  stage(Bmat, col0, Bbuf[0], 1, 0);
  stage(Amat, row0, Abuf[1], 0, 64);
  if (t < 256) {
    yrow[t] = y[row0 + t];
    nAr[t] = nA[row0 + t];
  } else {
    const int c = t - 256;
    ycol[c] = y[col0 + c];
    nBc[c] = nB[col0 + c];
  }
  __syncthreads();   // full drain once; counted vmcnt from here on

  f32x4 acc[8][4] = {};
  bf16x8 aF[4][2], bF0[2][2], bF1[2][2];

  int cur = 0;
  for (int kt = 0; kt < NT; ++kt) {
    const int nxt = cur ^ 1;
    const int k1 = ((kt + 1) & (NT - 1)) * 64;
    const int k2 = ((kt + 2) & (NT - 1)) * 64;

    // ---- phase 0: quadrant (mh=0, nh=0); prefetch A-half1 of kt+1 ----
#pragma unroll
    for (int m = 0; m < 4; ++m) {
      aF[m][0] = ldA(cur, 0, m, 0);
      aF[m][1] = ldA(cur, 0, m, 1);
    }
#pragma unroll
    for (int n = 0; n < 2; ++n) {
      bF0[n][0] = ldB(cur, 0, n, 0);
      bF0[n][1] = ldB(cur, 0, n, 1);
    }
    stage(Amat, row0, Abuf[nxt], 1, k1);
    BAR();
    __builtin_amdgcn_s_setprio(1);
#pragma unroll
    for (int m = 0; m < 4; ++m)
#pragma unroll
      for (int n = 0; n < 2; ++n) {
        acc[m][n] = __builtin_amdgcn_mfma_f32_16x16x32_bf16(aF[m][0], bF0[n][0], acc[m][n], 0, 0, 0);
        acc[m][n] = __builtin_amdgcn_mfma_f32_16x16x32_bf16(aF[m][1], bF0[n][1], acc[m][n], 0, 0, 0);
      }
    __builtin_amdgcn_s_setprio(0);
    BAR();

    // ---- phase 1: quadrant (0,1); prefetch B-half0 of kt+1 ----
#pragma unroll
    for (int n = 0; n < 2; ++n) {
      bF1[n][0] = ldB(cur, 1, n, 0);
      bF1[n][1] = ldB(cur, 1, n, 1);
    }
    stage(Bmat, col0, Bbuf[nxt], 0, k1);
    BAR();
    __builtin_amdgcn_s_setprio(1);
#pragma unroll
    for (int m = 0; m < 4; ++m)
#pragma unroll
      for (int n = 0; n < 2; ++n) {
        acc[m][2 + n] = __builtin_amdgcn_mfma_f32_16x16x32_bf16(aF[m][0], bF1[n][0], acc[m][2 + n], 0, 0, 0);
        acc[m][2 + n] = __builtin_amdgcn_mfma_f32_16x16x32_bf16(aF[m][1], bF1[n][1], acc[m][2 + n], 0, 0, 0);
      }
    __builtin_amdgcn_s_setprio(0);
    BAR();

    // ---- phase 2: quadrant (1,0); prefetch B-half1 of kt+1 ----
#pragma unroll
    for (int m = 0; m < 4; ++m) {
      aF[m][0] = ldA(cur, 1, m, 0);
      aF[m][1] = ldA(cur, 1, m, 1);
    }
    stage(Bmat, col0, Bbuf[nxt], 1, k1);
    BAR();
    __builtin_amdgcn_s_setprio(1);
#pragma unroll
    for (int m = 0; m < 4; ++m)
#pragma unroll
      for (int n = 0; n < 2; ++n) {
        acc[4 + m][n] = __builtin_amdgcn_mfma_f32_16x16x32_bf16(aF[m][0], bF0[n][0], acc[4 + m][n], 0, 0, 0);
        acc[4 + m][n] = __builtin_amdgcn_mfma_f32_16x16x32_bf16(aF[m][1], bF0[n][1], acc[4 + m][n], 0, 0, 0);
      }
    __builtin_amdgcn_s_setprio(0);
    BAR();

    // ---- phase 3: quadrant (1,1); prefetch A-half0 of kt+2 into buf[cur];
    //      counted wait: 2 newest (just-issued) stay in flight ----
    stage(Amat, row0, Abuf[cur], 0, k2);
    asm volatile("s_waitcnt vmcnt(2)" ::: "memory");
    BAR();
    __builtin_amdgcn_s_setprio(1);
#pragma unroll
    for (int m = 0; m < 4; ++m)
#pragma unroll
      for (int n = 0; n < 2; ++n) {
        acc[4 + m][2 + n] = __builtin_amdgcn_mfma_f32_16x16x32_bf16(aF[m][0], bF1[n][0], acc[4 + m][2 + n], 0, 0, 0);
        acc[4 + m][2 + n] = __builtin_amdgcn_mfma_f32_16x16x32_bf16(aF[m][1], bF1[n][1], acc[4 + m][2 + n], 0, 0, 0);
      }
    __builtin_amdgcn_s_setprio(0);
    BAR();

    cur = nxt;
  }
  asm volatile("s_waitcnt vmcnt(0)" ::: "memory");

  // ---- epilogue: sq distance + mask + per-row reduce over tile's 256 cols --
  const int rbase = dir * MDIM + row0;
#pragma unroll
  for (int M = 0; M < 8; ++M) {
#pragma unroll
    for (int r = 0; r < 4; ++r) {
      const int row_loc = wr * 128 + M * 16 + lg * 4 + r;
      const float na = nAr[row_loc];
      const int yl = yrow[row_loc];
      float smax = 0.0f;
      float dmin = __int_as_float(0x7F800000);
#pragma unroll
      for (int N = 0; N < 4; ++N) {
        const int col_loc = wc * 64 + N * 16 + lr;
        const float sq = fmaxf(na + nBc[col_loc] - 2.0f * acc[M][N][r], 0.0f);
        if (ycol[col_loc] == yl) smax = fmaxf(smax, sq);
        else                     dmin = fminf(dmin, sq);
      }
#pragma unroll
      for (int off = 1; off < 16; off <<= 1) {
        smax = fmaxf(smax, __shfl_xor(smax, off));
        dmin = fminf(dmin, __shfl_xor(dmin, off));
      }
      if (lr == 0) {
        // nonneg floats: int compare == float compare -> order-independent
        atomicMax(&same_sq[rbase + row_loc], __float_as_int(smax));
        atomicMin(&diff_sq[rbase + row_loc], __float_as_int(dmin));
      }
    }
  }
}

// --- finalize: sqrt, relu, sum ---------------------------------------------
__global__ __launch_bounds__(256) void finalize_kernel(
    const int* __restrict__ same_sq, const int* __restrict__ diff_sq,
    float* __restrict__ out) {
  const int i = blockIdx.x * 256 + threadIdx.x;  // 8192 total
  const float sm = sqrtf(__int_as_float(same_sq[i]));
  const float dm = sqrtf(__int_as_float(diff_sq[i]));  // +inf if no diff label
  float l = fmaxf(sm - dm + 1.2f, 0.0f);
  for (int off = 32; off; off >>= 1) l += __shfl_down(l, off);
  __shared__ float part[4];
  const int w = threadIdx.x >> 6, lane = threadIdx.x & 63;
  if (lane == 0) part[w] = l;
  __syncthreads();
  if (threadIdx.x == 0) atomicAdd(out, part[0] + part[1] + part[2] + part[3]);
}

extern "C" void kernel_launch(void* const* d_in, const int* in_sizes, int n_in,
                              void* d_out, int out_size, void* d_ws, size_t ws_size,
                              hipStream_t stream) {
  const float* vf = (const float*)d_in[0];
  const float* iff = (const float*)d_in[1];
  const int* y = (const int*)d_in[2];
  float* out = (float*)d_out;

  char* ws = (char*)d_ws;
  unsigned short* vb = (unsigned short*)ws;                       // 8 MB
  unsigned short* ib = (unsigned short*)(ws + (8u << 20));        // 8 MB
  float* nv  = (float*)(ws + (16u << 20));
  float* ni  = nv + 4096;
  float* nvp = nv + 2 * 4096;
  float* nip = nv + 3 * 4096;
  int* same_sq = (int*)(nv + 4 * 4096);                           // [2][4096]
  int* diff_sq = same_sq + 2 * 4096;                              // [2][4096]

  hipMemsetAsync(d_out, 0, sizeof(float), stream);
  init_kernel<<<32, 256, 0, stream>>>(same_sq, diff_sq);
  prep_kernel<<<8192, 256, 0, stream>>>(vf, iff, vb, ib, nv, ni, nvp, nip);
  tri_gemm<<<dim3(16, 16, 2), 512, 0, stream>>>(vb, ib, nv, ni, nvp, nip, y,
                                                same_sq, diff_sq);
  finalize_kernel<<<32, 256, 0, stream>>>(same_sq, diff_sq, out);
}